// Round 12
// baseline (116.442 us; speedup 1.0000x reference)
//
#include <hip/hip_runtime.h>
#include <cstdint>

#define Bsz 4
#define Nn  256
#define OBSD 40
#define ACTD 8
#define HEADS 8
#define DIMD 32
#define Td  256
#define R   4   // rows per block

#define FMA4(accr, s, wv) \
    (accr).x = fmaf((s), (wv).x, (accr).x); \
    (accr).y = fmaf((s), (wv).y, (accr).y); \
    (accr).z = fmaf((s), (wv).z, (accr).z); \
    (accr).w = fmaf((s), (wv).w, (accr).w)

typedef __attribute__((address_space(3))) void       lds_void;
typedef const __attribute__((address_space(1))) void glb_void;

// Async global->LDS DMA, 16 B per lane. lds base must be wave-uniform; HW
// places lane c's 16 B at base + 16*c. gp is the per-lane global address.
__device__ __forceinline__ void dma16(const float* gp, const float* lds_base) {
    __builtin_amdgcn_global_load_lds(
        (glb_void*)(uintptr_t)gp,
        (lds_void*)(uint32_t)(uintptr_t)lds_base,   // low 32 bits = LDS offset
        16, 0, 0);
}

// K1: emb = relu(relu(obs @ We1 + be1) @ We2 + be2), R=4 rows per block.
// grid = 256 blocks x 512 threads. Blocks 0/1 zero snh/shid.
// We1 fully DMA-staged; We2 streamed in 8 DMA double-buffered tiles of 32 rows.
__global__ __launch_bounds__(512, 1) void k_emb(
        const float* __restrict__ x,
        const float* __restrict__ We1, const float* __restrict__ be1,
        const float* __restrict__ We2, const float* __restrict__ be2,
        float* __restrict__ emb,
        float* __restrict__ snh, float* __restrict__ shid) {
    int g = blockIdx.x, t = threadIdx.x;
    int wv = t >> 6, c = t & 63;
    int row0 = g * R;
    int b = row0 >> 8, n0 = row0 & 255;

    __shared__ float  stage[2][32][Td];   // 64 KB: We2 tiles (stage[1] = We1 rows 0..31 at start)
    __shared__ float4 part[8][R][64];     // 32 KB: wave partials; first 8 KB = We1 rows 32..39 at start
    __shared__ float4 obs_t[OBSD];
    __shared__ float4 h1_t[Td];
    float* partF = (float*)part;

    // Prologue DMAs: We2 tile 0 -> stage[0]; We1 (40 rows) -> stage[1] + partF.
#pragma unroll
    for (int i = 0; i < 4; ++i) {
        int slot = wv * 4 + i;
        dma16(We2 + slot * Td + 4 * c, &stage[0][slot][0]);
    }
#pragma unroll
    for (int i = 0; i < 5; ++i) {
        int r = wv * 5 + i;
        if (r < OBSD) {
            float* dst = (r < 32) ? &stage[1][r][0] : &partF[(r - 32) * Td];
            dma16(We1 + r * Td + 4 * c, dst);
        }
    }

    if (g == 0)      { for (int i = t; i < Bsz * Td; i += 512) snh[i]  = 0.f; }
    else if (g == 1) { for (int i = t; i < Bsz * Td; i += 512) shid[i] = 0.f; }
    if (t < R * OBSD) {
        int r = t & 3, k = t >> 2;
        ((float*)&obs_t[k])[r] = x[(b * (Nn + 1) + n0 + r) * OBSD + k];
    }
    __syncthreads();   // drains all prologue DMAs (vmcnt(0) before s_barrier)

    // Layer 1 (K=40) from LDS-resident We1: threads 0..255, col t.
    if (t < Td) {
        float bias1 = be1[t];
        float a1[R] = {bias1, bias1, bias1, bias1};
#pragma unroll
        for (int k = 0; k < OBSD; ++k) {
            float w = (k < 32) ? stage[1][k][t] : partF[(k - 32) * Td + t];
            float4 ov = obs_t[k];
            a1[0] = fmaf(ov.x, w, a1[0]);
            a1[1] = fmaf(ov.y, w, a1[1]);
            a1[2] = fmaf(ov.z, w, a1[2]);
            a1[3] = fmaf(ov.w, w, a1[3]);
        }
        h1_t[t] = make_float4(fmaxf(a1[0], 0.f), fmaxf(a1[1], 0.f),
                              fmaxf(a1[2], 0.f), fmaxf(a1[3], 0.f));
    }
    __syncthreads();

    // Layer 2: 8 tiles x 32 We2-rows, DMA double-buffered; wave wv owns
    // rows wv*4+i of each tile (stages and consumes its own slots).
    float4 a2[R] = {};
    for (int tile = 0; tile < 8; ++tile) {
        int buf = tile & 1;
        if (tile + 1 < 8) {
#pragma unroll
            for (int i = 0; i < 4; ++i) {
                int slot = wv * 4 + i;
                dma16(We2 + ((tile + 1) * 32 + slot) * Td + 4 * c,
                      &stage[buf ^ 1][slot][0]);
            }
        }
#pragma unroll
        for (int i = 0; i < 4; ++i) {
            int slot = wv * 4 + i;
            int k = tile * 32 + slot;
            float4 wvv = *(const float4*)&stage[buf][slot][4 * c];
            float4 hv = h1_t[k];
            FMA4(a2[0], hv.x, wvv);
            FMA4(a2[1], hv.y, wvv);
            FMA4(a2[2], hv.z, wvv);
            FMA4(a2[3], hv.w, wvv);
        }
        __syncthreads();
    }

#pragma unroll
    for (int r = 0; r < R; ++r) part[wv][r][c] = a2[r];
    __syncthreads();
    if (t < Td) {
        int c2 = t >> 2, j = t & 3;
#pragma unroll
        for (int r = 0; r < R; ++r) {
            float v = be2[t];
#pragma unroll
            for (int w2 = 0; w2 < 8; ++w2) v += ((const float*)&part[w2][r][c2])[j];
            emb[(row0 + r) * Td + t] = fmaxf(v, 0.f);
        }
    }
}

// K2: fused ne + Wn/Wh column-sum, R=4 m-rows per block, grid (64,4) x 512.
// Phase 1: emb rows in 8 DMA-dbuf tiles of 32. Phase 2: Wn+Wh in 16 tiles of 16.
__global__ __launch_bounds__(512, 1) void k_fused(
        const float* __restrict__ adj, const float* __restrict__ emb,
        const float* __restrict__ Wn, const float* __restrict__ bn,
        const float* __restrict__ Wh, const float* __restrict__ bh,
        float* __restrict__ snh, float* __restrict__ shid) {
    int g = blockIdx.x, b = blockIdx.y;
    int t = threadIdx.x;
    int wv = t >> 6, c = t & 63;
    int m0 = g * R;

    __shared__ float  stage[2][32][Td];   // 64 KB
    __shared__ float4 arow_t[Nn];         // 4 KB
    __shared__ float4 nrow_t[Td];         // 4 KB
    __shared__ float4 partN[8][R][64];    // 32 KB
    __shared__ float4 partH[8][R][64];    // 32 KB

    const float* eb = emb + b * Nn * Td;

    // Prologue: DMA emb tile 0 (rows wv*4+i).
#pragma unroll
    for (int i = 0; i < 4; ++i) {
        int slot = wv * 4 + i;
        dma16(eb + slot * Td + 4 * c, &stage[0][slot][0]);
    }
    if (t < Td)
        arow_t[t] = make_float4(adj[(m0 + 0) * Nn + t], adj[(m0 + 1) * Nn + t],
                                adj[(m0 + 2) * Nn + t], adj[(m0 + 3) * Nn + t]);
    __syncthreads();

    // Phase 1: ne. Wave wv accumulates rows {32*tile + wv*4 + i}.
    float4 aN[R] = {};
    for (int tile = 0; tile < 8; ++tile) {
        int buf = tile & 1;
        if (tile + 1 < 8) {
#pragma unroll
            for (int i = 0; i < 4; ++i) {
                int slot = wv * 4 + i;
                dma16(eb + ((tile + 1) * 32 + slot) * Td + 4 * c,
                      &stage[buf ^ 1][slot][0]);
            }
        }
#pragma unroll
        for (int i = 0; i < 4; ++i) {
            int slot = wv * 4 + i;
            int n = tile * 32 + slot;
            float4 ev = *(const float4*)&stage[buf][slot][4 * c];
            float4 ar = arow_t[n];
            FMA4(aN[0], ar.x, ev);
            FMA4(aN[1], ar.y, ev);
            FMA4(aN[2], ar.z, ev);
            FMA4(aN[3], ar.w, ev);
        }
        __syncthreads();
    }
#pragma unroll
    for (int r = 0; r < R; ++r) partN[wv][r][c] = aN[r];
    // Prologue phase 2: Wn/Wh tile 0 -> stage[0] (slots 0..15 Wn, 16..31 Wh).
#pragma unroll
    for (int i = 0; i < 2; ++i) {
        int kl = wv * 2 + i;
        dma16(Wn + kl * Td + 4 * c, &stage[0][kl][0]);
        dma16(Wh + kl * Td + 4 * c, &stage[0][16 + kl][0]);
    }
    __syncthreads();
    if (t < Td) {
        int c2 = t >> 2, j = t & 3;
        float nr[R];
#pragma unroll
        for (int r = 0; r < R; ++r) {
            float v = 0.f;
#pragma unroll
            for (int w2 = 0; w2 < 8; ++w2) v += ((const float*)&partN[w2][r][c2])[j];
            nr[r] = v;
        }
        nrow_t[t] = make_float4(nr[0], nr[1], nr[2], nr[3]);
    }
    __syncthreads();

    // Phase 2: 16 tiles x 16 k-rows; wave wv owns k_local = 2wv + {0,1}.
    float4 sN[R] = {};
    float4 sH[R] = {};
    for (int tile = 0; tile < 16; ++tile) {
        int buf = tile & 1;
        if (tile + 1 < 16) {
#pragma unroll
            for (int i = 0; i < 2; ++i) {
                int kl = wv * 2 + i, k = (tile + 1) * 16 + kl;
                dma16(Wn + k * Td + 4 * c, &stage[buf ^ 1][kl][0]);
                dma16(Wh + k * Td + 4 * c, &stage[buf ^ 1][16 + kl][0]);
            }
        }
#pragma unroll
        for (int i = 0; i < 2; ++i) {
            int kl = wv * 2 + i, k = tile * 16 + kl;
            float4 wn4 = *(const float4*)&stage[buf][kl][4 * c];
            float4 wh4 = *(const float4*)&stage[buf][16 + kl][4 * c];
            float4 nv = nrow_t[k];
            FMA4(sN[0], nv.x, wn4);  FMA4(sH[0], nv.x, wh4);
            FMA4(sN[1], nv.y, wn4);  FMA4(sH[1], nv.y, wh4);
            FMA4(sN[2], nv.z, wn4);  FMA4(sH[2], nv.z, wh4);
            FMA4(sN[3], nv.w, wn4);  FMA4(sH[3], nv.w, wh4);
        }
        __syncthreads();
    }
#pragma unroll
    for (int r = 0; r < R; ++r) { partN[wv][r][c] = sN[r]; partH[wv][r][c] = sH[r]; }
    __syncthreads();

    if (t < Td) {
        int c2 = t >> 2, j = t & 3;
        float bnt = bn[t], bht = bh[t];
        float rs1 = 0.f, rs2 = 0.f;
#pragma unroll
        for (int r = 0; r < R; ++r) {
            float v1 = bnt, v2 = bht;
#pragma unroll
            for (int w2 = 0; w2 < 8; ++w2) {
                v1 += ((const float*)&partN[w2][r][c2])[j];
                v2 += ((const float*)&partH[w2][r][c2])[j];
            }
            rs1 += fmaxf(v1, 0.f);
            rs2 += fmaxf(v2, 0.f);
        }
        atomicAdd(&snh[b * Td + t], rs1);
        atomicAdd(&shid[b * Td + t], rs2);
    }
}

// K3: per-batch target row -> ah -> softmax over DIM per head -> mean -> Wa.
// 512 threads; Wl streamed in 8 DMA-dbuf tiles of 32 rows.
__global__ __launch_bounds__(512, 1) void k_final(
        const float* __restrict__ x, const float* __restrict__ emb,
        const float* __restrict__ Wl, const float* __restrict__ bl,
        const float* __restrict__ snh, const float* __restrict__ shid,
        const float* __restrict__ Wa, const float* __restrict__ ba,
        float* __restrict__ out) {
    int b = blockIdx.x;
    int t = threadIdx.x;
    int wv = t >> 6, c = t & 63;

    __shared__ float  stage[2][32][Td];   // 64 KB
    __shared__ float4 partL[8][64];       // 8 KB
    __shared__ float erow[Td], lg[Td], p[Td], od[DIMD];

#pragma unroll
    for (int i = 0; i < 4; ++i) {
        int slot = wv * 4 + i;
        dma16(Wl + slot * Td + 4 * c, &stage[0][slot][0]);
    }
    int tgt = (int)x[(b * (Nn + 1) + Nn) * OBSD + 0];
    tgt = tgt < 0 ? 0 : (tgt > Nn - 1 ? Nn - 1 : tgt);
    if (t < Td) erow[t] = emb[(b * Nn + tgt) * Td + t];
    __syncthreads();

    float4 aL = {};
    for (int tile = 0; tile < 8; ++tile) {
        int buf = tile & 1;
        if (tile + 1 < 8) {
#pragma unroll
            for (int i = 0; i < 4; ++i) {
                int slot = wv * 4 + i;
                dma16(Wl + ((tile + 1) * 32 + slot) * Td + 4 * c,
                      &stage[buf ^ 1][slot][0]);
            }
        }
#pragma unroll
        for (int i = 0; i < 4; ++i) {
            int slot = wv * 4 + i;
            int k = tile * 32 + slot;
            float4 wlv = *(const float4*)&stage[buf][slot][4 * c];
            FMA4(aL, erow[k], wlv);
        }
        __syncthreads();
    }
    partL[wv][c] = aL;
    __syncthreads();

    if (t < Td) {
        int c2 = t >> 2, j = t & 3;
        float acc = bl[t];
#pragma unroll
        for (int w2 = 0; w2 < 8; ++w2) acc += ((const float*)&partL[w2][c2])[j];
        lg[t] = fmaxf(acc, 0.f) * snh[b * Td + t];
    }
    __syncthreads();
    if (t < Td) {
        int h = t & 7;
        float mx = -1e30f;
#pragma unroll
        for (int d = 0; d < DIMD; ++d) mx = fmaxf(mx, lg[d * HEADS + h]);
        float se = 0.f;
#pragma unroll
        for (int d = 0; d < DIMD; ++d) se += __expf(lg[d * HEADS + h] - mx);
        p[t] = (__expf(lg[t] - mx) / se) * shid[b * Td + t];
    }
    __syncthreads();
    if (t < DIMD) {
        float s = 0.f;
#pragma unroll
        for (int hh = 0; hh < HEADS; ++hh) s += p[t * HEADS + hh];
        od[t] = s * (1.f / HEADS);
    }
    __syncthreads();
    if (t < ACTD) {
        float s = ba[t];
#pragma unroll
        for (int d = 0; d < DIMD; ++d) s = fmaf(od[d], Wa[d * ACTD + t], s);
        out[b * ACTD + t] = s;
    }
}

extern "C" void kernel_launch(void* const* d_in, const int* in_sizes, int n_in,
                              void* d_out, int out_size, void* d_ws, size_t ws_size,
                              hipStream_t stream) {
    const float* x   = (const float*)d_in[0];
    const float* adj = (const float*)d_in[1];
    const float* We1 = (const float*)d_in[2];
    const float* be1 = (const float*)d_in[3];
    const float* We2 = (const float*)d_in[4];
    const float* be2 = (const float*)d_in[5];
    const float* Wl  = (const float*)d_in[6];
    const float* bl  = (const float*)d_in[7];
    const float* Wn  = (const float*)d_in[8];
    const float* bn  = (const float*)d_in[9];
    const float* Wh  = (const float*)d_in[10];
    const float* bh  = (const float*)d_in[11];
    const float* Wa  = (const float*)d_in[12];
    const float* ba  = (const float*)d_in[13];
    float* out = (float*)d_out;

    // ws layout: emb f32[B*N*T] (1 MB) | snh f32[B*T] | shid f32[B*T]
    float* emb  = (float*)d_ws;
    float* snh  = emb + Bsz * Nn * Td;
    float* shid = snh + Bsz * Td;

    k_emb<<<dim3(Bsz * Nn / R), dim3(512), 0, stream>>>(x, We1, be1, We2, be2,
                                                        emb, snh, shid);
    k_fused<<<dim3(Nn / R, Bsz), dim3(512), 0, stream>>>(adj, emb, Wn, bn, Wh, bh,
                                                         snh, shid);
    k_final<<<dim3(Bsz), dim3(512), 0, stream>>>(x, emb, Wl, bl, snh, shid,
                                                 Wa, ba, out);
}